// Round 10
// baseline (58.501 us; speedup 1.0000x reference)
//
#include <hip/hip_runtime.h>
#include <hip/hip_bf16.h>
#include <hip/hip_fp16.h>

// GaussianSmoothing (2,1,192,192,192) f32, separable K=13 sigma=2.
// Model: VMEM-instruction-issue bound (~1 inst/cy/CU). Minimize VMEM count.
// Pass 1 blur_w : W-blur, 4 quads (16 floats)/thread: 8 f4 loads + 2 uint4
//                 f16 stores.            f32 x -> f16 tmp1
// Pass 2 colH   : H march, 2 x-adjacent quads (uint4)/thread, CH=16.
//                 f16 tmp1 -> f16 tmp2
// Pass 3 colD   : D march, uint4/thread, CH=16, f32 stores.
//                 f16 tmp2 -> f32 d_out

#define DIM 192
#define DIM2 (192 * 192)
#define NIMG 2
#define TOTAL (NIMG * DIM * DIM2)   // 14,155,776 floats
#define NQ (TOTAL / 4)              // 3,538,944 quads (4 floats each)
#define NPAIR (NQ / 2)              // 1,769,472 quad-pairs (8 floats, 24/row)

#define GTAPS                                                     \
    constexpr float G[13] = {                                     \
        2.2159242e-03f, 8.7641505e-03f, 2.6995483e-02f,           \
        6.4758800e-02f, 1.2098536e-01f, 1.7603266e-01f,           \
        1.9947114e-01f, 1.7603266e-01f, 1.2098536e-01f,           \
        6.4758800e-02f, 2.6995483e-02f, 8.7641505e-03f,           \
        2.2159242e-03f };

// ---- f16 pack/unpack ------------------------------------------------------
__device__ __forceinline__ void ld_h8(const uint4* __restrict__ p,
                                      float4& lo, float4& hi) {
    uint4 u = *p;
    __half2 a = *(__half2*)&u.x, b = *(__half2*)&u.y;
    __half2 c = *(__half2*)&u.z, d = *(__half2*)&u.w;
    lo = make_float4(__low2float(a), __high2float(a),
                     __low2float(b), __high2float(b));
    hi = make_float4(__low2float(c), __high2float(c),
                     __low2float(d), __high2float(d));
}
__device__ __forceinline__ uint4 st_h8(float4 lo, float4 hi) {
    __half2 a = __floats2half2_rn(lo.x, lo.y), b = __floats2half2_rn(lo.z, lo.w);
    __half2 c = __floats2half2_rn(hi.x, hi.y), d = __floats2half2_rn(hi.z, hi.w);
    uint4 u;
    u.x = *(unsigned*)&a; u.y = *(unsigned*)&b;
    u.z = *(unsigned*)&c; u.w = *(unsigned*)&d;
    return u;
}

// ---------------------------------------------------------------------------
// Pass 1: W-blur, FOUR quads (16 floats) per thread. Window = 8 quads
// [4g-2 .. 4g+5], clamped + 0/1-masked (branch-free). 8 loads + 2 uint4
// stores = 2.5 VMEM per output quad. Grid = NQ/4/256 = 3456 blocks.
// ---------------------------------------------------------------------------
__global__ __launch_bounds__(256) void blur_w(const float4* __restrict__ in,
                                              uint4* __restrict__ out) {
    GTAPS
    const int t = blockIdx.x * 256 + threadIdx.x;   // group id (4 quads)
    const int g = t % 12;                           // group within row
    const int rowq = (t / 12) * 48;                 // row base, quad units
    const int rowp = (t / 12) * 24;                 // row base, pair units

    // f[m] = rowfloat[16g - 8 + m], m = 0..31 (zero outside row)
    float f[32];
#pragma unroll
    for (int d = 0; d < 8; ++d) {
        int qq = 4 * g - 2 + d;
        float4 v;
        if (d >= 2 && d <= 5) {                     // always valid
            v = in[rowq + qq];
        } else {
            const float m = (qq >= 0 && qq < 48) ? 1.0f : 0.0f;
            qq = min(max(qq, 0), 47);
            v = in[rowq + qq];
            v.x *= m; v.y *= m; v.z *= m; v.w *= m;
        }
        *(float4*)&f[d * 4] = v;
    }

    float o[16];
#pragma unroll
    for (int j = 0; j < 16; ++j) {
        float a = 0.0f;
#pragma unroll
        for (int k = 0; k < 13; ++k) a += G[k] * f[j + 2 + k];
        o[j] = a;
    }
    out[rowp + 2 * g]     = st_h8(*(float4*)&o[0], *(float4*)&o[4]);
    out[rowp + 2 * g + 1] = st_h8(*(float4*)&o[8], *(float4*)&o[12]);
}

// ---------------------------------------------------------------------------
// Passes 2/3: axis march, one uint4 (2 x-adjacent quads, 8 floats) per
// thread-column; CH=16 outputs (+12 halo = 28 steps); 13 rolling {lo,hi}
// accumulator pairs. f32 math.
//   column c: base = (c / Q) * M + (c % Q)   (uint4 units)
//   H: Q=24 (pairs/row),   M=4608 (plane),  S=24
//   D: Q=4608 (pairs/plane), M=884736 (img), S=4608
// ncols = 9216; chunks = 12; block = 128 -> grid = 864 (1728 waves).
// ---------------------------------------------------------------------------
#define CHUNK 16
#define NSTEP (CHUNK + 12)   // 28

template <int Q, int M, int S, bool OUT_F32>
__global__ __launch_bounds__(128) void col_blur(const uint4* __restrict__ in,
                                                void* __restrict__ out_) {
    GTAPS
    uint4* __restrict__ out16 = (uint4*)out_;
    float4* __restrict__ out32 = (float4*)out_;
    const int gt = blockIdx.x * 128 + threadIdx.x;
    const int chunk = gt / 9216;           // uniform per block (9216%128==0)
    const int c = gt % 9216;
    const int base = (c / Q) * M + (c % Q);
    const int d0 = chunk * CHUNK;

    float4 alo[13], ahi[13];
#pragma unroll
    for (int j = 0; j < 13; ++j) {
        alo[j] = make_float4(0.f, 0.f, 0.f, 0.f);
        ahi[j] = make_float4(0.f, 0.f, 0.f, 0.f);
    }

#pragma unroll
    for (int s = 0; s < NSTEP; ++s) {
        const int i = d0 - 6 + s;
        float4 vlo = make_float4(0.f, 0.f, 0.f, 0.f);
        float4 vhi = make_float4(0.f, 0.f, 0.f, 0.f);
        if (i >= 0 && i < DIM) ld_h8(&in[base + i * S], vlo, vhi);
#pragma unroll
        for (int j = 0; j < 13; ++j) {
            const float g = G[12 - j];
            alo[j].x += g * vlo.x; alo[j].y += g * vlo.y;
            alo[j].z += g * vlo.z; alo[j].w += g * vlo.w;
            ahi[j].x += g * vhi.x; ahi[j].y += g * vhi.y;
            ahi[j].z += g * vhi.z; ahi[j].w += g * vhi.w;
        }
        if (s >= 12) {
            const int o = base + (i - 6) * S;
            if (OUT_F32) {
                out32[2 * o]     = alo[0];
                out32[2 * o + 1] = ahi[0];
            } else {
                out16[o] = st_h8(alo[0], ahi[0]);
            }
        }
#pragma unroll
        for (int j = 0; j < 12; ++j) { alo[j] = alo[j + 1]; ahi[j] = ahi[j + 1]; }
        alo[12] = make_float4(0.f, 0.f, 0.f, 0.f);
        ahi[12] = make_float4(0.f, 0.f, 0.f, 0.f);
    }
}

extern "C" void kernel_launch(void* const* d_in, const int* in_sizes, int n_in,
                              void* d_out, int out_size, void* d_ws, size_t ws_size,
                              hipStream_t stream) {
    const float* x = (const float*)d_in[0];
    float* out = (float*)d_out;
    uint4* tmp1 = (uint4*)d_ws;                // f16, 28.3 MB (NPAIR uint4)
    uint4* tmp2 = ((uint4*)d_ws) + NPAIR;      // f16, 28.3 MB

    // Pass 1: W one-shot (4 quads/thread), f32 x -> f16 tmp1
    blur_w<<<NQ / 4 / 256, 256, 0, stream>>>((const float4*)x, tmp1);
    // Pass 2: H axis (stride 24 pairs), f16 -> f16
    col_blur<24, 4608, 24, false><<<864, 128, 0, stream>>>(tmp1, (void*)tmp2);
    // Pass 3: D axis (stride 4608 pairs), f16 -> f32 out
    col_blur<4608, 884736, 4608, true><<<864, 128, 0, stream>>>(tmp2, (void*)out);
}

// Round 11
// 43.443 us; speedup vs baseline: 1.3466x; 1.3466x over previous
//
#include <hip/hip_runtime.h>
#include <hip/hip_bf16.h>
#include <hip/hip_fp16.h>

// GaussianSmoothing (2,1,192,192,192) f32, separable K=13 sigma=2.
// Model: latency/TLP-bound; maximize waves + upfront MLP, minimize FMA.
// Pass 1 blur_w : W-blur, 2 quads/thread (R9-proven), f32 x -> f16 tmp1
// Pass 2 colH   : H direct-form, CH=12, all 24 inputs loaded upfront.
//                 f16 tmp1 -> f16 tmp2
// Pass 3 colD   : D direct-form, CH=12, f32 stores. f16 tmp2 -> f32 d_out

#define DIM 192
#define DIM2 (192 * 192)
#define NIMG 2
#define TOTAL (NIMG * DIM * DIM2)   // 14,155,776 floats
#define NQ (TOTAL / 4)              // 3,538,944 quads (4 elems, 48/row)
#define NPAIR (NQ / 2)              // 1,769,472 quad-pairs (24/row)

#define GTAPS                                                     \
    constexpr float G[13] = {                                     \
        2.2159242e-03f, 8.7641505e-03f, 2.6995483e-02f,           \
        6.4758800e-02f, 1.2098536e-01f, 1.7603266e-01f,           \
        1.9947114e-01f, 1.7603266e-01f, 1.2098536e-01f,           \
        6.4758800e-02f, 2.6995483e-02f, 8.7641505e-03f,           \
        2.2159242e-03f };

// ---- f16 helpers ----------------------------------------------------------
__device__ __forceinline__ float4 ld_h4(const uint2* __restrict__ p) {
    uint2 u = *p;
    __half2 h0 = *(__half2*)&u.x;
    __half2 h1 = *(__half2*)&u.y;
    return make_float4(__low2float(h0), __high2float(h0),
                       __low2float(h1), __high2float(h1));
}
__device__ __forceinline__ uint2 st_h4(float4 v) {
    __half2 h0 = __floats2half2_rn(v.x, v.y);
    __half2 h1 = __floats2half2_rn(v.z, v.w);
    uint2 u;
    u.x = *(unsigned*)&h0;
    u.y = *(unsigned*)&h1;
    return u;
}

// ---------------------------------------------------------------------------
// Pass 1: W-blur, TWO quads (8 floats) per thread (R9-proven). Window = 6
// quads [2jp-2 .. 2jp+3], clamped + 0/1-masked (branch-free). One 16B uint4
// store of 8 f16 values. Grid = NPAIR/256 = 6912 blocks.
// ---------------------------------------------------------------------------
__global__ __launch_bounds__(256) void blur_w(const float4* __restrict__ in,
                                              uint4* __restrict__ out) {
    GTAPS
    const int j = blockIdx.x * 256 + threadIdx.x;   // pair id
    const int jp = j % 24;                          // pair within row
    const int rowq = (j / 24) * 48;                 // row base, quad units

    float f[24];
#pragma unroll
    for (int d = 0; d < 6; ++d) {
        int qq = 2 * jp - 2 + d;
        const float m = (qq >= 0 && qq < 48) ? 1.0f : 0.0f;
        qq = min(max(qq, 0), 47);
        float4 v = in[rowq + qq];
        if (d < 2 || d > 3) {                       // d=2,3 always valid
            v.x *= m; v.y *= m; v.z *= m; v.w *= m;
        }
        *(float4*)&f[d * 4] = v;
    }

    float o[8];
#pragma unroll
    for (int t = 0; t < 8; ++t) {
        float a = 0.0f;
#pragma unroll
        for (int k = 0; k < 13; ++k) a += G[k] * f[t + 2 + k];
        o[t] = a;
    }
    uint2 lo = st_h4(make_float4(o[0], o[1], o[2], o[3]));
    uint2 hi = st_h4(make_float4(o[4], o[5], o[6], o[7]));
    uint4 r; r.x = lo.x; r.y = lo.y; r.z = hi.x; r.w = hi.y;
    out[j] = r;
}

// ---------------------------------------------------------------------------
// Passes 2/3: DIRECT-FORM axis blur. Thread owns one f16-quad column (uint2),
// loads all CH+12=24 inputs upfront (deep MLP), then computes CH=12 outputs
// at 13 FMA/output. chunk is block-uniform; edge chunks (d0=0 / d0=180) use
// compile-time clipped bodies, interior has no masking at all.
//   column c: base = (c / Q) * M + (c % Q)   (uint2 = quad units)
//   H: Q=48, M=9216, S=48     D: Q=9216, M=1769472, S=9216
// ncols = 18432; chunks = 16; block = 128 -> grid = 2304 (4608 waves).
// ---------------------------------------------------------------------------
#define CH 12
#define NSTEP (CH + 12)     // 24
#define NCHUNK (DIM / CH)   // 16

template <int S, bool OUT_F32, int CLIP>
__device__ __forceinline__ void col_body(const uint2* __restrict__ in,
                                         void* __restrict__ out_,
                                         int base, int d0) {
    GTAPS
    float4 v[NSTEP];
#pragma unroll
    for (int s = 0; s < NSTEP; ++s) {
        bool valid = true;
        if (CLIP < 0) valid = (s >= 6);          // d0 == 0:   i = s-6
        if (CLIP > 0) valid = (s < NSTEP - 6);   // d0 == 180: i = 174+s
        if (valid) v[s] = ld_h4(&in[base + (d0 - 6 + s) * S]);
        else       v[s] = make_float4(0.f, 0.f, 0.f, 0.f);
    }
#pragma unroll
    for (int t = 0; t < CH; ++t) {
        float4 a = make_float4(0.f, 0.f, 0.f, 0.f);
#pragma unroll
        for (int k = 0; k < 13; ++k) {
            const float g = G[k];
            a.x += g * v[t + k].x;
            a.y += g * v[t + k].y;
            a.z += g * v[t + k].z;
            a.w += g * v[t + k].w;
        }
        const int o = base + (d0 + t) * S;
        if (OUT_F32) ((float4*)out_)[o] = a;
        else         ((uint2*)out_)[o] = st_h4(a);
    }
}

template <int Q, int M, int S, bool OUT_F32>
__global__ __launch_bounds__(128) void col_blur(const uint2* __restrict__ in,
                                                void* __restrict__ out_) {
    const int gt = blockIdx.x * 128 + threadIdx.x;
    const int chunk = gt / 18432;          // block-uniform (18432 % 128 == 0)
    const int c = gt % 18432;
    const int base = (c / Q) * M + (c % Q);
    const int d0 = chunk * CH;

    if (chunk == 0)                col_body<S, OUT_F32, -1>(in, out_, base, d0);
    else if (chunk == NCHUNK - 1)  col_body<S, OUT_F32, +1>(in, out_, base, d0);
    else                           col_body<S, OUT_F32,  0>(in, out_, base, d0);
}

extern "C" void kernel_launch(void* const* d_in, const int* in_sizes, int n_in,
                              void* d_out, int out_size, void* d_ws, size_t ws_size,
                              hipStream_t stream) {
    const float* x = (const float*)d_in[0];
    float* out = (float*)d_out;
    uint2* tmp1 = (uint2*)d_ws;               // f16, 28.3 MB (NQ uint2)
    uint2* tmp2 = ((uint2*)d_ws) + NQ;        // f16, 28.3 MB

    // Pass 1: W one-shot (2 quads/thread), f32 x -> f16 tmp1
    blur_w<<<NPAIR / 256, 256, 0, stream>>>((const float4*)x, (uint4*)tmp1);
    // Pass 2: H axis (stride 48 quads), f16 -> f16, direct form
    col_blur<48, 9216, 48, false><<<2304, 128, 0, stream>>>(tmp1, (void*)tmp2);
    // Pass 3: D axis (stride 9216 quads), f16 -> f32 out, direct form
    col_blur<9216, 1769472, 9216, true><<<2304, 128, 0, stream>>>(tmp2, (void*)out);
}

// Round 13
// 42.564 us; speedup vs baseline: 1.3744x; 1.0207x over previous
//
#include <hip/hip_runtime.h>
#include <hip/hip_bf16.h>
#include <hip/hip_fp16.h>

// GaussianSmoothing (2,1,192,192,192) f32, separable K=13 sigma=2.
// R13 = R11 + nontemporal final stores (colD) via ext_vector_type (the HIP
// float4 wrapper type is rejected by __builtin_nontemporal_store).
// Theory: harness dirties all of L3 (268 MB 0xAA fill) before each replay;
// our L3 allocations evict those dirty lines -> hidden writeback competes
// with our cold reads. NT stores for the never-re-read 57 MB output remove
// ~57 MB of in-window evictions.
// Pass 1 blur_w : W-blur, 2 quads/thread, f32 x -> f16 tmp1
// Pass 2 colH   : H direct-form, CH=12, f16 tmp1 -> f16 tmp2
// Pass 3 colD   : D direct-form, CH=12, NT f32 stores, f16 tmp2 -> f32 d_out

#define DIM 192
#define DIM2 (192 * 192)
#define NIMG 2
#define TOTAL (NIMG * DIM * DIM2)   // 14,155,776 floats
#define NQ (TOTAL / 4)              // 3,538,944 quads (4 elems, 48/row)
#define NPAIR (NQ / 2)              // 1,769,472 quad-pairs (24/row)

typedef float f32x4 __attribute__((ext_vector_type(4)));

#define GTAPS                                                     \
    constexpr float G[13] = {                                     \
        2.2159242e-03f, 8.7641505e-03f, 2.6995483e-02f,           \
        6.4758800e-02f, 1.2098536e-01f, 1.7603266e-01f,           \
        1.9947114e-01f, 1.7603266e-01f, 1.2098536e-01f,           \
        6.4758800e-02f, 2.6995483e-02f, 8.7641505e-03f,           \
        2.2159242e-03f };

// ---- f16 helpers ----------------------------------------------------------
__device__ __forceinline__ float4 ld_h4(const uint2* __restrict__ p) {
    uint2 u = *p;
    __half2 h0 = *(__half2*)&u.x;
    __half2 h1 = *(__half2*)&u.y;
    return make_float4(__low2float(h0), __high2float(h0),
                       __low2float(h1), __high2float(h1));
}
__device__ __forceinline__ uint2 st_h4(float4 v) {
    __half2 h0 = __floats2half2_rn(v.x, v.y);
    __half2 h1 = __floats2half2_rn(v.z, v.w);
    uint2 u;
    u.x = *(unsigned*)&h0;
    u.y = *(unsigned*)&h1;
    return u;
}

// ---------------------------------------------------------------------------
// Pass 1: W-blur, TWO quads (8 floats) per thread. Window = 6 quads
// [2jp-2 .. 2jp+3], clamped + 0/1-masked (branch-free). One 16B uint4 store
// of 8 f16 values. Grid = NPAIR/256 = 6912 blocks.
// ---------------------------------------------------------------------------
__global__ __launch_bounds__(256) void blur_w(const float4* __restrict__ in,
                                              uint4* __restrict__ out) {
    GTAPS
    const int j = blockIdx.x * 256 + threadIdx.x;   // pair id
    const int jp = j % 24;                          // pair within row
    const int rowq = (j / 24) * 48;                 // row base, quad units

    float f[24];
#pragma unroll
    for (int d = 0; d < 6; ++d) {
        int qq = 2 * jp - 2 + d;
        const float m = (qq >= 0 && qq < 48) ? 1.0f : 0.0f;
        qq = min(max(qq, 0), 47);
        float4 v = in[rowq + qq];
        if (d < 2 || d > 3) {                       // d=2,3 always valid
            v.x *= m; v.y *= m; v.z *= m; v.w *= m;
        }
        *(float4*)&f[d * 4] = v;
    }

    float o[8];
#pragma unroll
    for (int t = 0; t < 8; ++t) {
        float a = 0.0f;
#pragma unroll
        for (int k = 0; k < 13; ++k) a += G[k] * f[t + 2 + k];
        o[t] = a;
    }
    uint2 lo = st_h4(make_float4(o[0], o[1], o[2], o[3]));
    uint2 hi = st_h4(make_float4(o[4], o[5], o[6], o[7]));
    uint4 r; r.x = lo.x; r.y = lo.y; r.z = hi.x; r.w = hi.y;
    out[j] = r;
}

// ---------------------------------------------------------------------------
// Passes 2/3: DIRECT-FORM axis blur. Thread owns one f16-quad column (uint2),
// loads all CH+12=24 inputs upfront (deep MLP), then computes CH=12 outputs
// at 13 FMA/output. chunk is block-uniform; edge chunks use compile-time
// clipped bodies, interior has no masking.
//   column c: base = (c / Q) * M + (c % Q)   (quad units)
//   H: Q=48, M=9216, S=48     D: Q=9216, M=1769472, S=9216
// ncols = 18432; chunks = 16; block = 128 -> grid = 2304 (4608 waves).
// OUT_F32 (final pass) stores are NONTEMPORAL: no L3 allocation.
// ---------------------------------------------------------------------------
#define CH 12
#define NSTEP (CH + 12)     // 24
#define NCHUNK (DIM / CH)   // 16

template <int S, bool OUT_F32, int CLIP>
__device__ __forceinline__ void col_body(const uint2* __restrict__ in,
                                         void* __restrict__ out_,
                                         int base, int d0) {
    GTAPS
    float4 v[NSTEP];
#pragma unroll
    for (int s = 0; s < NSTEP; ++s) {
        bool valid = true;
        if (CLIP < 0) valid = (s >= 6);          // d0 == 0:   i = s-6
        if (CLIP > 0) valid = (s < NSTEP - 6);   // d0 == 180: i = 174+s
        if (valid) v[s] = ld_h4(&in[base + (d0 - 6 + s) * S]);
        else       v[s] = make_float4(0.f, 0.f, 0.f, 0.f);
    }
#pragma unroll
    for (int t = 0; t < CH; ++t) {
        float4 a = make_float4(0.f, 0.f, 0.f, 0.f);
#pragma unroll
        for (int k = 0; k < 13; ++k) {
            const float g = G[k];
            a.x += g * v[t + k].x;
            a.y += g * v[t + k].y;
            a.z += g * v[t + k].z;
            a.w += g * v[t + k].w;
        }
        const int o = base + (d0 + t) * S;
        if (OUT_F32) {
            f32x4 av;
            av.x = a.x; av.y = a.y; av.z = a.z; av.w = a.w;
            __builtin_nontemporal_store(av, &((f32x4*)out_)[o]);
        } else {
            ((uint2*)out_)[o] = st_h4(a);
        }
    }
}

template <int Q, int M, int S, bool OUT_F32>
__global__ __launch_bounds__(128) void col_blur(const uint2* __restrict__ in,
                                                void* __restrict__ out_) {
    const int gt = blockIdx.x * 128 + threadIdx.x;
    const int chunk = gt / 18432;          // block-uniform (18432 % 128 == 0)
    const int c = gt % 18432;
    const int base = (c / Q) * M + (c % Q);
    const int d0 = chunk * CH;

    if (chunk == 0)                col_body<S, OUT_F32, -1>(in, out_, base, d0);
    else if (chunk == NCHUNK - 1)  col_body<S, OUT_F32, +1>(in, out_, base, d0);
    else                           col_body<S, OUT_F32,  0>(in, out_, base, d0);
}

extern "C" void kernel_launch(void* const* d_in, const int* in_sizes, int n_in,
                              void* d_out, int out_size, void* d_ws, size_t ws_size,
                              hipStream_t stream) {
    const float* x = (const float*)d_in[0];
    float* out = (float*)d_out;
    uint2* tmp1 = (uint2*)d_ws;               // f16, 28.3 MB (NQ uint2)
    uint2* tmp2 = ((uint2*)d_ws) + NQ;        // f16, 28.3 MB

    // Pass 1: W one-shot (2 quads/thread), f32 x -> f16 tmp1
    blur_w<<<NPAIR / 256, 256, 0, stream>>>((const float4*)x, (uint4*)tmp1);
    // Pass 2: H axis (stride 48 quads), f16 -> f16, direct form
    col_blur<48, 9216, 48, false><<<2304, 128, 0, stream>>>(tmp1, (void*)tmp2);
    // Pass 3: D axis (stride 9216 quads), f16 -> f32 out, direct form, NT stores
    col_blur<9216, 1769472, 9216, true><<<2304, 128, 0, stream>>>(tmp2, (void*)out);
}